// Round 2
// baseline (244.861 us; speedup 1.0000x reference)
//
#include <hip/hip_runtime.h>

#define B_   8
#define N_   2048
#define FIN  256
#define FOUT 64
#define ALPHA 0.2f

typedef __attribute__((ext_vector_type(8))) short bf16x8;
typedef __attribute__((ext_vector_type(8))) unsigned short u16x8;
typedef __attribute__((ext_vector_type(4))) unsigned short u16x4;
typedef __attribute__((ext_vector_type(4))) float f32x4;

__device__ __forceinline__ float b2f(unsigned short u) {
    union { unsigned int u; float f; } v; v.u = ((unsigned int)u) << 16; return v.f;
}
// round-to-nearest-even f32 -> bf16
__device__ __forceinline__ unsigned short f2b(float f) {
    union { float f; unsigned int u; } v; v.f = f;
    unsigned int r = v.u + 0x7FFFu + ((v.u >> 16) & 1u);
    return (unsigned short)(r >> 16);
}

// ---- Kernel 1 (fused): h-GEMM + transpose + src/dst projections + adj-pack ----
// 1024 blocks x 16 rows. R2: appends a streaming phase that packs adj (134 MB
// int32, 1 bit of info per word) into a 4 MB bitmask. This moves the dominant
// HBM stream out of the barrier-locked attention kernel into a coalesce-perfect
// linear scan (fill-like BW efficiency), and makes k_attn's adj input
// L2-resident (512 KB/batch shared by 64 blocks).
__global__ __launch_bounds__(256) void k_hgemm_tr(
    const float* __restrict__ x, const int* __restrict__ adj,
    const float* __restrict__ W, const float* __restrict__ bW,
    const float* __restrict__ asrc, const float* __restrict__ adst,
    unsigned short* __restrict__ hT, float* __restrict__ src, float* __restrict__ dst,
    unsigned int* __restrict__ adjm)
{
    __shared__ unsigned short tileT[FOUT * 20];   // [f][row], pitch 20 shorts
    __shared__ float as_s[FOUT], ad_s[FOUT];

    const int tid = threadIdx.x;
    const int wv = tid >> 6, lane = tid & 63;
    const int quad = lane >> 4, col = lane & 15;
    const int f = wv * 16 + col;

    if (tid < FOUT) { as_s[tid] = asrc[tid]; ad_s[tid] = adst[tid]; }

    bf16x8 Bf[8];
    #pragma unroll
    for (int kk = 0; kk < 8; ++kk) {
        bf16x8 t;
        #pragma unroll
        for (int j = 0; j < 8; ++j)
            t[j] = (short)f2b(W[(kk * 32 + quad * 8 + j) * FOUT + f]);
        Bf[kk] = t;
    }
    const float bias = bW[f];
    const int r0 = blockIdx.x * 16;
    const int b = r0 >> 11;
    const int j0b = r0 & (N_ - 1);

    f32x4 acc = {0.f, 0.f, 0.f, 0.f};
    #pragma unroll
    for (int kk = 0; kk < 8; ++kk) {
        const float* xp = x + (size_t)(r0 + col) * FIN + kk * 32 + quad * 8;
        float4 x0 = *(const float4*)xp;
        float4 x1 = *(const float4*)(xp + 4);
        bf16x8 Af;
        Af[0] = (short)f2b(x0.x); Af[1] = (short)f2b(x0.y);
        Af[2] = (short)f2b(x0.z); Af[3] = (short)f2b(x0.w);
        Af[4] = (short)f2b(x1.x); Af[5] = (short)f2b(x1.y);
        Af[6] = (short)f2b(x1.z); Af[7] = (short)f2b(x1.w);
        acc = __builtin_amdgcn_mfma_f32_16x16x32_bf16(Af, Bf[kk], acc, 0, 0, 0);
    }
    #pragma unroll
    for (int reg = 0; reg < 4; ++reg)
        tileT[f * 20 + quad * 4 + reg] = f2b(acc[reg] + bias);
    __syncthreads();

    {   // src/dst dots: 16 rows x 16 f-groups of 4
        const int i = tid >> 4, fb = (tid & 15) * 4;
        float sp = 0.f, dp = 0.f;
        #pragma unroll
        for (int k = 0; k < 4; ++k) {
            float hv = b2f(tileT[(fb + k) * 20 + i]);
            sp += hv * as_s[fb + k]; dp += hv * ad_s[fb + k];
        }
        sp += __shfl_xor(sp, 1); sp += __shfl_xor(sp, 2);
        sp += __shfl_xor(sp, 4); sp += __shfl_xor(sp, 8);
        dp += __shfl_xor(dp, 1); dp += __shfl_xor(dp, 2);
        dp += __shfl_xor(dp, 4); dp += __shfl_xor(dp, 8);
        if ((tid & 15) == 0) { src[r0 + i] = sp; dst[r0 + i] = dp; }
    }
    {   // hT writeout: 64 f x 16 cols, 8B per thread
        const int fq = tid >> 2, ic = (tid & 3) * 4;
        unsigned short* op = hT + (size_t)(b * FOUT + fq) * N_ + j0b + ic;
        *(u16x4*)op = *(const u16x4*)&tileT[fq * 20 + ic];
    }

    // ---- adj pack phase: 1 Mi words total, 1024 words/block ----
    // Word w covers adj ints [32w, 32w+32); bit k = (adj[32w+k] > 0).
    // Lane l packs ints [8l, 8l+8) of its wave's 512-int chunk, then two
    // xor-shuffle combines assemble full words in lanes with (l&3)==0.
    {
        const int ln = lane;
        const size_t wave_words0 = (size_t)blockIdx.x * 1024 + wv * 16;
        #pragma unroll 4
        for (int r = 0; r < 16; ++r) {
            const size_t wb0 = wave_words0 + (size_t)r * 64;
            const int* ap = adj + wb0 * 32 + ln * 8;
            int4 v0 = *(const int4*)ap;
            int4 v1 = *(const int4*)(ap + 4);
            unsigned int bits = 0;
            bits |= (unsigned int)(v0.x > 0) << 0;
            bits |= (unsigned int)(v0.y > 0) << 1;
            bits |= (unsigned int)(v0.z > 0) << 2;
            bits |= (unsigned int)(v0.w > 0) << 3;
            bits |= (unsigned int)(v1.x > 0) << 4;
            bits |= (unsigned int)(v1.y > 0) << 5;
            bits |= (unsigned int)(v1.z > 0) << 6;
            bits |= (unsigned int)(v1.w > 0) << 7;
            unsigned int s1 = __shfl_xor(bits, 1);
            unsigned int w1 = (bits << ((ln & 1) * 8)) | (s1 << ((~ln & 1) * 8));
            unsigned int s2 = __shfl_xor(w1, 2);
            unsigned int w2 = (w1 << ((ln & 2) * 8)) | (s2 << ((~ln & 2) * 8));
            if ((ln & 3) == 0) adjm[wb0 + (ln >> 2)] = w2;
        }
    }
}

// ---- Kernel 2: fused attention (bitmask adj; all inputs L2-resident) ----
// HBM traffic now ~8 MB (out writes + cold misses); mask (512 KB/batch),
// dst (8 KB/batch), hT (256 KB/batch) all served from L2.
// Keeps the R1-verified structure: w_s double-buffer, single non-draining
// LDS barrier per tile, register-double-buffered B-fragments.
#define ATT_TILE(MC, Dc0,Dc1,Dc2,Dc3, MN, Dn0,Dn1,Dn2,Dn3, BfC, BfN, BUF, JT)         \
{                                                                                      \
    const float dv[16] = {Dc0.x,Dc0.y,Dc0.z,Dc0.w, Dc1.x,Dc1.y,Dc1.z,Dc1.w,            \
                          Dc2.x,Dc2.y,Dc2.z,Dc2.w, Dc3.x,Dc3.y,Dc3.z,Dc3.w};           \
    u16x8 p0, p1; float ls = 0.f;                                                      \
    _Pragma("unroll")                                                                  \
    for (int k = 0; k < 16; ++k) {                                                     \
        float e = srci + dv[k];                                                        \
        e = e > 0.f ? e : ALPHA * e;                                                   \
        float wval = ((MC >> k) & 1u) ? __expf(e) : 0.f;                               \
        unsigned short wb = f2b(wval);                                                 \
        ls += b2f(wb);   /* denominator from SAME rounded weights as numerator */      \
        if (k < 8) p0[k] = wb; else p1[k - 8] = wb;                                    \
    }                                                                                  \
    lsum += ls;                                                                        \
    {   unsigned short* q = &w_s[BUF][il * 136 + jg * 16];                             \
        *(u16x8*)q = p0; *(u16x8*)(q + 8) = p1; }                                      \
    {   /* depth-1 prefetch of next tile's mask+dst (L2, ~200cy) */                    \
        const int jn = ((JT) + 1) & 15;                                                \
        MN = mbase[jn * 8];                                                            \
        Dn0 = *(const float4*)(dstbase + jn * 128);                                    \
        Dn1 = *(const float4*)(dstbase + jn * 128 + 4);                                \
        Dn2 = *(const float4*)(dstbase + jn * 128 + 8);                                \
        Dn3 = *(const float4*)(dstbase + jn * 128 + 12); }                             \
    /* LDS-only barrier: do NOT drain vmcnt (prefetches stay in flight) */             \
    asm volatile("s_waitcnt lgkmcnt(0)\n\ts_barrier" ::: "memory");                    \
    {   /* depth-1 prefetch of next tile's B-fragments (L2 hit) */                     \
        const int jn = (((JT) + 1) & 15) * 128;                                        \
        BfN[0] = *(const bf16x8*)(hfbase + jn);                                        \
        BfN[1] = *(const bf16x8*)(hfbase + jn + 32);                                   \
        BfN[2] = *(const bf16x8*)(hfbase + jn + 64);                                   \
        BfN[3] = *(const bf16x8*)(hfbase + jn + 96); }                                 \
    _Pragma("unroll")                                                                  \
    for (int kk = 0; kk < 4; ++kk) {                                                   \
        bf16x8 A0 = *(const bf16x8*)&w_s[BUF][col * 136 + kk * 32 + quad * 8];         \
        bf16x8 A1 = *(const bf16x8*)&w_s[BUF][(16 + col) * 136 + kk * 32 + quad * 8];  \
        acc0 = __builtin_amdgcn_mfma_f32_16x16x32_bf16(A0, BfC[kk], acc0, 0, 0, 0);    \
        acc1 = __builtin_amdgcn_mfma_f32_16x16x32_bf16(A1, BfC[kk], acc1, 0, 0, 0);    \
    }                                                                                  \
}

__global__ __launch_bounds__(256) void k_attn(
    const unsigned short* __restrict__ adjm, const float* __restrict__ src,
    const float* __restrict__ dst, const unsigned short* __restrict__ hT,
    const float* __restrict__ abp, float* __restrict__ out)
{
    __shared__ unsigned short w_s[2][32 * 136];
    __shared__ float src_s[32];
    __shared__ float l_s[32];

    const int tid = threadIdx.x;
    const int wv = tid >> 6, lane = tid & 63;
    const int quad = lane >> 4, col = lane & 15;
    const int b = blockIdx.x >> 6;
    const int i0 = (blockIdx.x & 63) * 32;

    if (tid < 32) src_s[tid] = src[b * N_ + i0 + tid];
    __syncthreads();

    const int il = tid >> 3, jg = tid & 7;          // w-phase: row 0..31, j-group 0..7
    const float srci = src_s[il] + abp[0];
    // mask: 128 ushorts per row; tile jt occupies ushorts [jt*8, jt*8+8)
    const unsigned short* mbase = adjm + (size_t)(b * N_ + i0 + il) * 128 + jg;
    const float* dstbase = dst + b * N_ + jg * 16;
    // B-fragment base: lane (wv,quad,col) reads hT[f = wv*16+col][jn + kk*32 + quad*8 ..]
    const unsigned short* hfbase = hT + (size_t)(b * FOUT + wv * 16 + col) * N_ + quad * 8;

    // prologue: tile 0's mask/dst/B-fragments
    unsigned int mE = mbase[0], mO;
    float4 dE0 = *(const float4*)(dstbase);
    float4 dE1 = *(const float4*)(dstbase + 4);
    float4 dE2 = *(const float4*)(dstbase + 8);
    float4 dE3 = *(const float4*)(dstbase + 12);
    float4 dO0, dO1, dO2, dO3;
    bf16x8 bfE[4], bfO[4];
    bfE[0] = *(const bf16x8*)(hfbase);
    bfE[1] = *(const bf16x8*)(hfbase + 32);
    bfE[2] = *(const bf16x8*)(hfbase + 64);
    bfE[3] = *(const bf16x8*)(hfbase + 96);

    float lsum = 0.f;
    f32x4 acc0 = {0, 0, 0, 0}, acc1 = {0, 0, 0, 0};

    for (int it = 0; it < 8; ++it) {
        const int jt = it * 2;
        ATT_TILE(mE, dE0, dE1, dE2, dE3, mO, dO0, dO1, dO2, dO3, bfE, bfO, 0, jt)
        ATT_TILE(mO, dO0, dO1, dO2, dO3, mE, dE0, dE1, dE2, dE3, bfO, bfE, 1, jt + 1)
    }

    lsum += __shfl_xor(lsum, 1);
    lsum += __shfl_xor(lsum, 2);
    lsum += __shfl_xor(lsum, 4);
    if (jg == 0) l_s[il] = lsum;
    __syncthreads();

    #pragma unroll
    for (int m = 0; m < 2; ++m) {
        f32x4 a = m ? acc1 : acc0;
        #pragma unroll
        for (int reg = 0; reg < 4; ++reg) {
            int row = m * 16 + quad * 4 + reg;
            float l = l_s[row];
            l = l > 0.f ? l : 1.f;
            float v = a[reg] / l;
            v = v > 0.f ? v : (__expf(v) - 1.f);   // ELU(alpha=1)
            out[(size_t)(b * N_ + i0 + row) * FOUT + wv * 16 + col] = v;
        }
    }
}

extern "C" void kernel_launch(void* const* d_in, const int* in_sizes, int n_in,
                              void* d_out, int out_size, void* d_ws, size_t ws_size,
                              hipStream_t stream)
{
    const float* x    = (const float*)d_in[0];
    const int*   adj  = (const int*)d_in[1];
    const float* W    = (const float*)d_in[2];
    const float* bW   = (const float*)d_in[3];
    const float* asrc = (const float*)d_in[4];
    const float* adst = (const float*)d_in[5];
    const float* abp  = (const float*)d_in[6];
    float* out = (float*)d_out;

    char* ws = (char*)d_ws;
    unsigned short* hT = (unsigned short*)ws;                               // 2 MB
    float* src = (float*)(ws + (size_t)2 * 1024 * 1024);                    // 64 KB
    float* dst = (float*)(ws + (size_t)2 * 1024 * 1024 + 64 * 1024);        // 64 KB
    unsigned int* adjm = (unsigned int*)(ws + (size_t)4 * 1024 * 1024);     // 4 MB

    k_hgemm_tr<<<1024, 256, 0, stream>>>(x, adj, W, bW, asrc, adst, hT, src, dst, adjm);
    k_attn<<<512, 256, 0, stream>>>((const unsigned short*)adjm, src, dst, hT, abp, out);
}

// Round 3
// 243.896 us; speedup vs baseline: 1.0040x; 1.0040x over previous
//
#include <hip/hip_runtime.h>

#define B_   8
#define N_   2048
#define FIN  256
#define FOUT 64
#define ALPHA 0.2f

typedef __attribute__((ext_vector_type(8))) short bf16x8;
typedef __attribute__((ext_vector_type(8))) unsigned short u16x8;
typedef __attribute__((ext_vector_type(4))) unsigned short u16x4;
typedef __attribute__((ext_vector_type(4))) float f32x4;

__device__ __forceinline__ float b2f(unsigned short u) {
    union { unsigned int u; float f; } v; v.u = ((unsigned int)u) << 16; return v.f;
}
// round-to-nearest-even f32 -> bf16
__device__ __forceinline__ unsigned short f2b(float f) {
    union { float f; unsigned int u; } v; v.f = f;
    unsigned int r = v.u + 0x7FFFu + ((v.u >> 16) & 1u);
    return (unsigned short)(r >> 16);
}

// ---- Kernel 1 (fused): h-GEMM + transpose + src/dst projections ----
// R1 form (1024 blocks x 16 rows). R2's adj-pack phase DELETED: it cost
// exactly the 134MB re-read (+21.8us) and bought nothing, since k_attn is
// not BW-bound (measured R2).
__global__ __launch_bounds__(256) void k_hgemm_tr(
    const float* __restrict__ x, const float* __restrict__ W,
    const float* __restrict__ bW, const float* __restrict__ asrc,
    const float* __restrict__ adst,
    unsigned short* __restrict__ hT, float* __restrict__ src, float* __restrict__ dst)
{
    __shared__ unsigned short tileT[FOUT * 20];   // [f][row], pitch 20 shorts
    __shared__ float as_s[FOUT], ad_s[FOUT];

    const int tid = threadIdx.x;
    const int wv = tid >> 6, lane = tid & 63;
    const int quad = lane >> 4, col = lane & 15;
    const int f = wv * 16 + col;

    if (tid < FOUT) { as_s[tid] = asrc[tid]; ad_s[tid] = adst[tid]; }

    bf16x8 Bf[8];
    #pragma unroll
    for (int kk = 0; kk < 8; ++kk) {
        bf16x8 t;
        #pragma unroll
        for (int j = 0; j < 8; ++j)
            t[j] = (short)f2b(W[(kk * 32 + quad * 8 + j) * FOUT + f]);
        Bf[kk] = t;
    }
    const float bias = bW[f];
    const int r0 = blockIdx.x * 16;
    const int b = r0 >> 11;
    const int j0b = r0 & (N_ - 1);

    f32x4 acc = {0.f, 0.f, 0.f, 0.f};
    #pragma unroll
    for (int kk = 0; kk < 8; ++kk) {
        const float* xp = x + (size_t)(r0 + col) * FIN + kk * 32 + quad * 8;
        float4 x0 = *(const float4*)xp;
        float4 x1 = *(const float4*)(xp + 4);
        bf16x8 Af;
        Af[0] = (short)f2b(x0.x); Af[1] = (short)f2b(x0.y);
        Af[2] = (short)f2b(x0.z); Af[3] = (short)f2b(x0.w);
        Af[4] = (short)f2b(x1.x); Af[5] = (short)f2b(x1.y);
        Af[6] = (short)f2b(x1.z); Af[7] = (short)f2b(x1.w);
        acc = __builtin_amdgcn_mfma_f32_16x16x32_bf16(Af, Bf[kk], acc, 0, 0, 0);
    }
    #pragma unroll
    for (int reg = 0; reg < 4; ++reg)
        tileT[f * 20 + quad * 4 + reg] = f2b(acc[reg] + bias);
    __syncthreads();

    {   // src/dst dots: 16 rows x 16 f-groups of 4
        const int i = tid >> 4, fb = (tid & 15) * 4;
        float sp = 0.f, dp = 0.f;
        #pragma unroll
        for (int k = 0; k < 4; ++k) {
            float hv = b2f(tileT[(fb + k) * 20 + i]);
            sp += hv * as_s[fb + k]; dp += hv * ad_s[fb + k];
        }
        sp += __shfl_xor(sp, 1); sp += __shfl_xor(sp, 2);
        sp += __shfl_xor(sp, 4); sp += __shfl_xor(sp, 8);
        dp += __shfl_xor(dp, 1); dp += __shfl_xor(dp, 2);
        dp += __shfl_xor(dp, 4); dp += __shfl_xor(dp, 8);
        if ((tid & 15) == 0) { src[r0 + i] = sp; dst[r0 + i] = dp; }
    }
    {   // hT writeout: 64 f x 16 cols, 8B per thread
        const int fq = tid >> 2, ic = (tid & 3) * 4;
        unsigned short* op = hT + (size_t)(b * FOUT + fq) * N_ + j0b + ic;
        *(u16x4*)op = *(const u16x4*)&tileT[fq * 20 + ic];
    }
}

// ---- Kernel 2: attention, j-SPLIT x4 (flash-style additive split) ----
// R2 measurement proved k_attn is NOT BW-bound (removing 130MB of its HBM
// fetch changed nothing). Remaining theory: latency-bound at 2 blocks/CU
// with a 16-tile serial chain. Fix: 2048 blocks (4 j-splits x 512 i-tiles),
// each handling 512 j in 4 tiles -> 4 blocks/CU (launch_bounds-enforced),
// serial chain 4x shorter. Softmax here is purely additive (no running
// max), so splits compose: write partial numerator/denominator, reduce in k3.
#define ATT_TILE(Aa,Ab,Ac,Ad, An0,An1,An2,An3, BfC, BfN, BUF, JT)                      \
{                                                                                      \
    /* dst JIT (L2-hot, 8KB/batch): saves 16 VGPR vs double-buffering */               \
    const float4 Dv0 = *(const float4*)(dstbase + (JT) * 128);                         \
    const float4 Dv1 = *(const float4*)(dstbase + (JT) * 128 + 4);                     \
    const float4 Dv2 = *(const float4*)(dstbase + (JT) * 128 + 8);                     \
    const float4 Dv3 = *(const float4*)(dstbase + (JT) * 128 + 12);                    \
    const int av[16] = {Aa.x,Aa.y,Aa.z,Aa.w, Ab.x,Ab.y,Ab.z,Ab.w,                      \
                        Ac.x,Ac.y,Ac.z,Ac.w, Ad.x,Ad.y,Ad.z,Ad.w};                     \
    const float dv[16] = {Dv0.x,Dv0.y,Dv0.z,Dv0.w, Dv1.x,Dv1.y,Dv1.z,Dv1.w,            \
                          Dv2.x,Dv2.y,Dv2.z,Dv2.w, Dv3.x,Dv3.y,Dv3.z,Dv3.w};           \
    u16x8 p0, p1; float ls = 0.f;                                                      \
    _Pragma("unroll")                                                                  \
    for (int k = 0; k < 16; ++k) {                                                     \
        float e = srci + dv[k];                                                        \
        e = e > 0.f ? e : ALPHA * e;                                                   \
        float wval = av[k] > 0 ? __expf(e) : 0.f;                                      \
        unsigned short wb = f2b(wval);                                                 \
        ls += b2f(wb);   /* denominator from SAME rounded weights as numerator */      \
        if (k < 8) p0[k] = wb; else p1[k - 8] = wb;                                    \
    }                                                                                  \
    lsum += ls;                                                                        \
    {   unsigned short* q = &w_s[BUF][il * 136 + jg * 16];                             \
        *(u16x8*)q = p0; *(u16x8*)(q + 8) = p1; }                                      \
    {   /* depth-1 adj prefetch (HBM latency must be covered) */                       \
        const int jn = (((JT) + 1) & 3) * 128;                                         \
        An0 = *(const int4*)(adjbase + jn);                                            \
        An1 = *(const int4*)(adjbase + jn + 4);                                        \
        An2 = *(const int4*)(adjbase + jn + 8);                                        \
        An3 = *(const int4*)(adjbase + jn + 12); }                                     \
    /* LDS-only barrier: adj prefetch stays in flight */                               \
    asm volatile("s_waitcnt lgkmcnt(0)\n\ts_barrier" ::: "memory");                    \
    {   /* depth-1 B-fragment prefetch (L2 hit) */                                     \
        const int jn = (((JT) + 1) & 3) * 128;                                         \
        BfN[0] = *(const bf16x8*)(hfbase + jn);                                        \
        BfN[1] = *(const bf16x8*)(hfbase + jn + 32);                                   \
        BfN[2] = *(const bf16x8*)(hfbase + jn + 64);                                   \
        BfN[3] = *(const bf16x8*)(hfbase + jn + 96); }                                 \
    _Pragma("unroll")                                                                  \
    for (int kk = 0; kk < 4; ++kk) {                                                   \
        bf16x8 A0 = *(const bf16x8*)&w_s[BUF][col * 136 + kk * 32 + quad * 8];         \
        bf16x8 A1 = *(const bf16x8*)&w_s[BUF][(16 + col) * 136 + kk * 32 + quad * 8];  \
        acc0 = __builtin_amdgcn_mfma_f32_16x16x32_bf16(A0, BfC[kk], acc0, 0, 0, 0);    \
        acc1 = __builtin_amdgcn_mfma_f32_16x16x32_bf16(A1, BfC[kk], acc1, 0, 0, 0);    \
    }                                                                                  \
}

__global__ __launch_bounds__(256, 4) void k_attn(
    const int* __restrict__ adj, const float* __restrict__ src,
    const float* __restrict__ dst, const unsigned short* __restrict__ hT,
    const float* __restrict__ abp,
    float* __restrict__ pnum, float* __restrict__ pden)
{
    __shared__ unsigned short w_s[2][32 * 136];
    __shared__ float src_s[32];

    const int tid = threadIdx.x;
    const int wv = tid >> 6, lane = tid & 63;
    const int quad = lane >> 4, col = lane & 15;
    const int s4 = blockIdx.x & 3;          // j-split id
    const int g  = blockIdx.x >> 2;         // i-tile id 0..511
    const int b  = g >> 6;
    const int i0 = (g & 63) * 32;
    const int j0 = s4 * 512;

    if (tid < 32) src_s[tid] = src[b * N_ + i0 + tid];
    __syncthreads();

    const int il = tid >> 3, jg = tid & 7;          // w-phase: row 0..31, j-group 0..7
    const float srci = src_s[il] + abp[0];
    const int* adjbase = adj + (size_t)(b * N_ + i0 + il) * N_ + j0 + jg * 16;
    const float* dstbase = dst + b * N_ + j0 + jg * 16;
    const unsigned short* hfbase = hT + (size_t)(b * FOUT + wv * 16 + col) * N_ + j0 + quad * 8;

    // prologue: tile 0 adj + B-fragments
    int4 aE0 = *(const int4*)(adjbase);
    int4 aE1 = *(const int4*)(adjbase + 4);
    int4 aE2 = *(const int4*)(adjbase + 8);
    int4 aE3 = *(const int4*)(adjbase + 12);
    int4 aO0, aO1, aO2, aO3;
    bf16x8 bfE[4], bfO[4];
    bfE[0] = *(const bf16x8*)(hfbase);
    bfE[1] = *(const bf16x8*)(hfbase + 32);
    bfE[2] = *(const bf16x8*)(hfbase + 64);
    bfE[3] = *(const bf16x8*)(hfbase + 96);

    float lsum = 0.f;
    f32x4 acc0 = {0, 0, 0, 0}, acc1 = {0, 0, 0, 0};

    ATT_TILE(aE0, aE1, aE2, aE3, aO0, aO1, aO2, aO3, bfE, bfO, 0, 0)
    ATT_TILE(aO0, aO1, aO2, aO3, aE0, aE1, aE2, aE3, bfO, bfE, 1, 1)
    ATT_TILE(aE0, aE1, aE2, aE3, aO0, aO1, aO2, aO3, bfE, bfO, 0, 2)
    ATT_TILE(aO0, aO1, aO2, aO3, aE0, aE1, aE2, aE3, bfO, bfE, 1, 3)

    lsum += __shfl_xor(lsum, 1);
    lsum += __shfl_xor(lsum, 2);
    lsum += __shfl_xor(lsum, 4);
    if (jg == 0) pden[(size_t)blockIdx.x * 32 + il] = lsum;

    float* pb = pnum + (size_t)blockIdx.x * 2048 + wv * 16 + col;
    #pragma unroll
    for (int m = 0; m < 2; ++m) {
        f32x4 a = m ? acc1 : acc0;
        #pragma unroll
        for (int reg = 0; reg < 4; ++reg)
            pb[(m * 16 + quad * 4 + reg) * 64] = a[reg];
    }
}

// ---- Kernel 3: split reduction + normalize + ELU ----
// 512 blocks (one per 32-row i-tile); reads 4 partials (16.8MB) + denoms.
__global__ __launch_bounds__(256) void k_reduce(
    const float* __restrict__ pnum, const float* __restrict__ pden,
    float* __restrict__ out)
{
    const int g = blockIdx.x;               // i-tile 0..511
    const int tid = threadIdx.x;
    const int f = tid & 63, ro = tid >> 6;  // 0..3
    const size_t base = (size_t)g * 4 * 2048;
    #pragma unroll
    for (int rr = 0; rr < 8; ++rr) {
        const int row = ro * 8 + rr;        // 0..31
        float num = 0.f, den = 0.f;
        #pragma unroll
        for (int s = 0; s < 4; ++s) {
            num += pnum[base + (size_t)s * 2048 + row * 64 + f];
            den += pden[(size_t)(g * 4 + s) * 32 + row];
        }
        den = den > 0.f ? den : 1.f;
        float v = num / den;
        v = v > 0.f ? v : (__expf(v) - 1.f);   // ELU(alpha=1)
        out[((size_t)g * 32 + row) * 64 + f] = v;
    }
}

extern "C" void kernel_launch(void* const* d_in, const int* in_sizes, int n_in,
                              void* d_out, int out_size, void* d_ws, size_t ws_size,
                              hipStream_t stream)
{
    const float* x    = (const float*)d_in[0];
    const int*   adj  = (const int*)d_in[1];
    const float* W    = (const float*)d_in[2];
    const float* bW   = (const float*)d_in[3];
    const float* asrc = (const float*)d_in[4];
    const float* adst = (const float*)d_in[5];
    const float* abp  = (const float*)d_in[6];
    float* out = (float*)d_out;

    char* ws = (char*)d_ws;
    unsigned short* hT = (unsigned short*)ws;                                // 2 MB
    float* src  = (float*)(ws + (size_t)2 * 1024 * 1024);                    // 64 KB
    float* dst  = (float*)(ws + (size_t)2 * 1024 * 1024 + 64 * 1024);        // 64 KB
    float* pnum = (float*)(ws + (size_t)4 * 1024 * 1024);                    // 16.8 MB
    float* pden = (float*)(ws + (size_t)21 * 1024 * 1024);                   // 256 KB

    k_hgemm_tr<<<1024, 256, 0, stream>>>(x, W, bW, asrc, adst, hT, src, dst);
    k_attn<<<2048, 256, 0, stream>>>(adj, src, dst, hT, abp, pnum, pden);
    k_reduce<<<512, 256, 0, stream>>>(pnum, pden, out);
}

// Round 4
// 243.023 us; speedup vs baseline: 1.0076x; 1.0036x over previous
//
#include <hip/hip_runtime.h>

#define B_   8
#define N_   2048
#define FIN  256
#define FOUT 64
#define ALPHA 0.2f
#define NSP  4                 // j-splits
#define JC   (N_ / NSP / 32)   // 16 chunks of 32 j per split

typedef __attribute__((ext_vector_type(8))) short bf16x8;
typedef __attribute__((ext_vector_type(8))) unsigned short u16x8;
typedef __attribute__((ext_vector_type(4))) unsigned short u16x4;
typedef __attribute__((ext_vector_type(4))) float f32x4;

__device__ __forceinline__ float b2f(unsigned short u) {
    union { unsigned int u; float f; } v; v.u = ((unsigned int)u) << 16; return v.f;
}
// round-to-nearest-even f32 -> bf16
__device__ __forceinline__ unsigned short f2b(float f) {
    union { float f; unsigned int u; } v; v.f = f;
    unsigned int r = v.u + 0x7FFFu + ((v.u >> 16) & 1u);
    return (unsigned short)(r >> 16);
}

// ---- Kernel 1 (fused): h-GEMM + transpose + src/dst projections ----
// R1 form, 1024 blocks x 16 rows. Unchanged (near its memory floor).
__global__ __launch_bounds__(256) void k_hgemm_tr(
    const float* __restrict__ x, const float* __restrict__ W,
    const float* __restrict__ bW, const float* __restrict__ asrc,
    const float* __restrict__ adst,
    unsigned short* __restrict__ hT, float* __restrict__ src, float* __restrict__ dst)
{
    __shared__ unsigned short tileT[FOUT * 20];   // [f][row], pitch 20 shorts
    __shared__ float as_s[FOUT], ad_s[FOUT];

    const int tid = threadIdx.x;
    const int wv = tid >> 6, lane = tid & 63;
    const int quad = lane >> 4, col = lane & 15;
    const int f = wv * 16 + col;

    if (tid < FOUT) { as_s[tid] = asrc[tid]; ad_s[tid] = adst[tid]; }

    bf16x8 Bf[8];
    #pragma unroll
    for (int kk = 0; kk < 8; ++kk) {
        bf16x8 t;
        #pragma unroll
        for (int j = 0; j < 8; ++j)
            t[j] = (short)f2b(W[(kk * 32 + quad * 8 + j) * FOUT + f]);
        Bf[kk] = t;
    }
    const float bias = bW[f];
    const int r0 = blockIdx.x * 16;
    const int b = r0 >> 11;
    const int j0b = r0 & (N_ - 1);

    f32x4 acc = {0.f, 0.f, 0.f, 0.f};
    #pragma unroll
    for (int kk = 0; kk < 8; ++kk) {
        const float* xp = x + (size_t)(r0 + col) * FIN + kk * 32 + quad * 8;
        float4 x0 = *(const float4*)xp;
        float4 x1 = *(const float4*)(xp + 4);
        bf16x8 Af;
        Af[0] = (short)f2b(x0.x); Af[1] = (short)f2b(x0.y);
        Af[2] = (short)f2b(x0.z); Af[3] = (short)f2b(x0.w);
        Af[4] = (short)f2b(x1.x); Af[5] = (short)f2b(x1.y);
        Af[6] = (short)f2b(x1.z); Af[7] = (short)f2b(x1.w);
        acc = __builtin_amdgcn_mfma_f32_16x16x32_bf16(Af, Bf[kk], acc, 0, 0, 0);
    }
    #pragma unroll
    for (int reg = 0; reg < 4; ++reg)
        tileT[f * 20 + quad * 4 + reg] = f2b(acc[reg] + bias);
    __syncthreads();

    {   // src/dst dots: 16 rows x 16 f-groups of 4
        const int i = tid >> 4, fb = (tid & 15) * 4;
        float sp = 0.f, dp = 0.f;
        #pragma unroll
        for (int k = 0; k < 4; ++k) {
            float hv = b2f(tileT[(fb + k) * 20 + i]);
            sp += hv * as_s[fb + k]; dp += hv * ad_s[fb + k];
        }
        sp += __shfl_xor(sp, 1); sp += __shfl_xor(sp, 2);
        sp += __shfl_xor(sp, 4); sp += __shfl_xor(sp, 8);
        dp += __shfl_xor(dp, 1); dp += __shfl_xor(dp, 2);
        dp += __shfl_xor(dp, 4); dp += __shfl_xor(dp, 8);
        if ((tid & 15) == 0) { src[r0 + i] = sp; dst[r0 + i] = dp; }
    }
    {   // hT writeout: 64 f x 16 cols, 8B per thread
        const int fq = tid >> 2, ic = (tid & 3) * 4;
        unsigned short* op = hT + (size_t)(b * FOUT + fq) * N_ + j0b + ic;
        *(u16x4*)op = *(const u16x4*)&tileT[fq * 20 + ic];
    }
}

// ---- Kernel 2: attention, barrier-free independent waves ----
// Each wave owns 16 i-rows and sweeps 512 j (split 4) in 32-j chunks.
// The MFMA A-fragment (lane = row l&15, k-slice (l>>4)*8) is computed
// DIRECTLY in registers from adj/dst/src: no LDS, no __syncthreads, no
// inter-wave coupling. adj (HBM stream, the 21us floor) is depth-1
// register-prefetched and never drained by a barrier. hT B-frags (L2-hot)
// also depth-1 prefetched; dst (L1-resident, 8KB/batch) loaded JIT.
#define CHUNK(AEa, AEb, HE0, HE1, HE2, HE3, AOa, AOb, HO0, HO1, HO2, HO3, T)        \
{                                                                                    \
    const int jn = (((T) + 1) & (JC - 1)) * 32;                                      \
    AOa = *(const int4*)(adjp + jn);                                                 \
    AOb = *(const int4*)(adjp + jn + 4);                                             \
    HO0 = *(const bf16x8*)(hfp + jn);                                                \
    HO1 = *(const bf16x8*)(hfp + 16 * N_ + jn);                                      \
    HO2 = *(const bf16x8*)(hfp + 32 * N_ + jn);                                      \
    HO3 = *(const bf16x8*)(hfp + 48 * N_ + jn);                                      \
    const int jc = (T) * 32;                                                         \
    const float4 Dv0 = *(const float4*)(dstp + jc);                                  \
    const float4 Dv1 = *(const float4*)(dstp + jc + 4);                              \
    const int av[8] = {AEa.x, AEa.y, AEa.z, AEa.w, AEb.x, AEb.y, AEb.z, AEb.w};      \
    const float dv[8] = {Dv0.x, Dv0.y, Dv0.z, Dv0.w, Dv1.x, Dv1.y, Dv1.z, Dv1.w};    \
    bf16x8 Af; float ls = 0.f;                                                       \
    _Pragma("unroll")                                                                \
    for (int k = 0; k < 8; ++k) {                                                    \
        float e = srci + dv[k];                                                      \
        e = e > 0.f ? e : ALPHA * e;                                                 \
        float wval = av[k] > 0 ? __expf(e) : 0.f;                                    \
        unsigned short wb = f2b(wval);                                               \
        ls += b2f(wb);   /* denominator from SAME rounded weights as numerator */    \
        Af[k] = (short)wb;                                                           \
    }                                                                                \
    lsum += ls;                                                                      \
    acc0 = __builtin_amdgcn_mfma_f32_16x16x32_bf16(Af, HE0, acc0, 0, 0, 0);          \
    acc1 = __builtin_amdgcn_mfma_f32_16x16x32_bf16(Af, HE1, acc1, 0, 0, 0);          \
    acc2 = __builtin_amdgcn_mfma_f32_16x16x32_bf16(Af, HE2, acc2, 0, 0, 0);          \
    acc3 = __builtin_amdgcn_mfma_f32_16x16x32_bf16(Af, HE3, acc3, 0, 0, 0);          \
}

__global__ __launch_bounds__(256) void k_attn(
    const int* __restrict__ adj, const float* __restrict__ src,
    const float* __restrict__ dst, const unsigned short* __restrict__ hT,
    const float* __restrict__ abp,
    float* __restrict__ pnum, float* __restrict__ pden)
{
    const int tid = threadIdx.x;
    const int wv = tid >> 6, lane = tid & 63;
    const int quad = lane >> 4, col = lane & 15;
    const int sp = blockIdx.x & 3;              // j-split 0..3
    const int rb = blockIdx.x >> 2;             // row-block 0..255 (64 rows)
    const int grow0 = rb * 64 + wv * 16;        // wave's first global row
    const int b = grow0 >> 11;
    const int j0 = sp * 512;

    const float srci = src[grow0 + col] + abp[0];   // lane's row = col
    const int* adjp = adj + (size_t)(grow0 + col) * N_ + j0 + quad * 8;
    const float* dstp = dst + (size_t)b * N_ + j0 + quad * 8;
    const unsigned short* hfp = hT + ((size_t)b * FOUT + col) * N_ + j0 + quad * 8;

    // prologue: chunk 0
    int4 aE0 = *(const int4*)(adjp);
    int4 aE1 = *(const int4*)(adjp + 4);
    bf16x8 hE0 = *(const bf16x8*)(hfp);
    bf16x8 hE1 = *(const bf16x8*)(hfp + 16 * N_);
    bf16x8 hE2 = *(const bf16x8*)(hfp + 32 * N_);
    bf16x8 hE3 = *(const bf16x8*)(hfp + 48 * N_);
    int4 aO0, aO1; bf16x8 hO0, hO1, hO2, hO3;

    float lsum = 0.f;
    f32x4 acc0 = {0, 0, 0, 0}, acc1 = {0, 0, 0, 0};
    f32x4 acc2 = {0, 0, 0, 0}, acc3 = {0, 0, 0, 0};

    for (int t = 0; t < JC; t += 2) {
        CHUNK(aE0, aE1, hE0, hE1, hE2, hE3, aO0, aO1, hO0, hO1, hO2, hO3, t)
        CHUNK(aO0, aO1, hO0, hO1, hO2, hO3, aE0, aE1, hE0, hE1, hE2, hE3, t + 1)
    }

    // denominator: sum the 4 k-slice partials for each row (lanes col, col+16,
    // col+32, col+48 all hold row=col partials)
    lsum += __shfl_xor(lsum, 16);
    lsum += __shfl_xor(lsum, 32);
    if (quad == 0) pden[(size_t)sp * (B_ * N_) + grow0 + col] = lsum;

    // partial numerator: C layout col=lane&15 (=f within group), row=quad*4+reg
    float* pb = pnum + ((size_t)sp * (B_ * N_) + grow0) * FOUT;
    #pragma unroll
    for (int fg = 0; fg < 4; ++fg) {
        f32x4 a = fg == 0 ? acc0 : fg == 1 ? acc1 : fg == 2 ? acc2 : acc3;
        #pragma unroll
        for (int reg = 0; reg < 4; ++reg)
            pb[(quad * 4 + reg) * FOUT + fg * 16 + col] = a[reg];
    }
}

// ---- Kernel 3: split reduction + normalize + ELU ----
__global__ __launch_bounds__(256) void k_reduce(
    const float* __restrict__ pnum, const float* __restrict__ pden,
    float* __restrict__ out)
{
    const int idx = blockIdx.x * 256 + threadIdx.x;   // 0..262143
    const int g = idx >> 4, f0 = (idx & 15) * 4;
    float nx = 0.f, ny = 0.f, nz = 0.f, nw = 0.f, den = 0.f;
    #pragma unroll
    for (int s = 0; s < NSP; ++s) {
        const float4 p = *(const float4*)&pnum[((size_t)s * (B_ * N_) + g) * FOUT + f0];
        nx += p.x; ny += p.y; nz += p.z; nw += p.w;
        den += pden[(size_t)s * (B_ * N_) + g];
    }
    den = den > 0.f ? den : 1.f;
    float4 v;
    v.x = nx / den; v.y = ny / den; v.z = nz / den; v.w = nw / den;
    v.x = v.x > 0.f ? v.x : (__expf(v.x) - 1.f);
    v.y = v.y > 0.f ? v.y : (__expf(v.y) - 1.f);
    v.z = v.z > 0.f ? v.z : (__expf(v.z) - 1.f);
    v.w = v.w > 0.f ? v.w : (__expf(v.w) - 1.f);
    *(float4*)&out[(size_t)g * FOUT + f0] = v;
}

extern "C" void kernel_launch(void* const* d_in, const int* in_sizes, int n_in,
                              void* d_out, int out_size, void* d_ws, size_t ws_size,
                              hipStream_t stream)
{
    const float* x    = (const float*)d_in[0];
    const int*   adj  = (const int*)d_in[1];
    const float* W    = (const float*)d_in[2];
    const float* bW   = (const float*)d_in[3];
    const float* asrc = (const float*)d_in[4];
    const float* adst = (const float*)d_in[5];
    const float* abp  = (const float*)d_in[6];
    float* out = (float*)d_out;

    char* ws = (char*)d_ws;
    unsigned short* hT = (unsigned short*)ws;                                // 2 MB
    float* src  = (float*)(ws + (size_t)2 * 1024 * 1024);                    // 64 KB
    float* dst  = (float*)(ws + (size_t)2 * 1024 * 1024 + 64 * 1024);        // 64 KB
    float* pnum = (float*)(ws + (size_t)4 * 1024 * 1024);                    // 16 MB
    float* pden = (float*)(ws + (size_t)20 * 1024 * 1024);                   // 256 KB

    k_hgemm_tr<<<1024, 256, 0, stream>>>(x, W, bW, asrc, adst, hT, src, dst);
    k_attn<<<1024, 256, 0, stream>>>(adj, src, dst, hT, abp, pnum, pden);
    k_reduce<<<1024, 256, 0, stream>>>(pnum, pden, out);
}